// Round 1
// baseline (811.890 us; speedup 1.0000x reference)
//
#include <hip/hip_runtime.h>

// KV cache roll-and-append:
//   out_k[b,h,l,:] = k_cache[b,h,l+1,:]  (l < 4095)
//   out_k[b,h,4095,:] = k[b,h,0,:]
// same for v. Shapes: B=4,H=32,L=4096,D=128, fp32.
// Pure streaming copy: ~1 GiB HBM traffic, floor ~170 us @ 6.3 TB/s.

constexpr long long N_PER_OUT = 4LL * 32 * 4096 * 128;   // 67,108,864 elements
constexpr int LOG2_ROW = 7;        // D = 128 = 2^7
constexpr int LOG2_BH = 19;        // L*D = 4096*128 = 2^19
constexpr int LAST_ROW = 4095;

__global__ __launch_bounds__(256)
void kv_roll_kernel(const float4* __restrict__ k_cache,
                    const float* __restrict__ k_new,
                    const float4* __restrict__ v_cache,
                    const float* __restrict__ v_new,
                    float4* __restrict__ out) {
    // select k vs v half via blockIdx.y
    const float4* cache = blockIdx.y ? v_cache : k_cache;
    const float*  ntok  = blockIdx.y ? v_new   : k_new;
    float4* o = out + (long long)blockIdx.y * (N_PER_OUT >> 2);

    long long i = (long long)blockIdx.x * blockDim.x + threadIdx.x; // float4 index
    long long e = i << 2;                                           // element offset
    int l = (int)((e >> LOG2_ROW) & (LAST_ROW)); // row within (b,h); 4095 mask since L=4096

    float4 val;
    if (l != LAST_ROW) {
        // shifted copy: src element = out element + 128  (=> +32 float4)
        val = cache[i + 32];
    } else {
        // last row: new token. bh = e >> 19, d = e & 127
        long long bh = e >> LOG2_BH;
        const float4* src = (const float4*)(ntok + bh * 128);
        val = src[(e & 127) >> 2];
    }
    o[i] = val;
}

extern "C" void kernel_launch(void* const* d_in, const int* in_sizes, int n_in,
                              void* d_out, int out_size, void* d_ws, size_t ws_size,
                              hipStream_t stream) {
    const float4* k_cache = (const float4*)d_in[0];
    const float4* v_cache = (const float4*)d_in[1];
    const float*  k_new   = (const float*)d_in[2];
    const float*  v_new   = (const float*)d_in[3];
    // d_in[4] = context_length (== L, so full roll) -- baked into the index math.
    float4* out = (float4*)d_out;

    const int block = 256;
    const long long n_vec = N_PER_OUT >> 2;           // 16,777,216 float4 per output
    dim3 grid((unsigned)(n_vec / block), 2, 1);       // 65536 x 2

    kv_roll_kernel<<<grid, block, 0, stream>>>(k_cache, k_new, v_cache, v_new, out);
}